// Round 3
// baseline (334.701 us; speedup 1.0000x reference)
//
#include <hip/hip_runtime.h>
#include <float.h>
#include <limits.h>

// RankLoss round 3: software-pipelined streaming.
// R2 post-mortem: one unit per wave -> lockstep load-stall phases (VALUBusy 38%,
// HBM 17%, nothing saturated). Fix: each wave processes several (row,matrix)
// units with a 2-stage ping-pong prefetch, so unit n+1's global loads are in
// flight while unit n's reduction computes. Targets are scalar-preloaded for
// all steps so the dependent x[target] load never heads a prefetch stage.

constexpr int B     = 32768;
constexpr int C_ENT = 1000;   // 250 float4
constexpr int C_REL = 500;    // 125 float4
constexpr float LOG2E = 1.4426950408889634f;

__device__ inline float fast_exp2(float x) {
#if __has_builtin(__builtin_amdgcn_exp2f)
  return __builtin_amdgcn_exp2f(x);
#else
  return exp2f(x);
#endif
}

template<int NK>
struct UnitData { float4 v[NK]; float xt; };

template<int NK, int C4>
__device__ inline void unit_load(const float* __restrict__ row, int lane, int target,
                                 UnitData<NK>& U) {
  const float4* row4 = (const float4*)row;
#pragma unroll
  for (int k = 0; k < NK; ++k) {
    U.v[k] = make_float4(-FLT_MAX, -FLT_MAX, -FLT_MAX, -FLT_MAX);
    const int i = lane + 64 * k;
    if (i < C4) U.v[k] = row4[i];   // exec-masked load over sentinel init
  }
  U.xt = row[target];
}

template<int NK>
__device__ inline float4 unit_compute(const UnitData<NK>& U, int lane) {
  // m1: local max tree + 6-stage butterfly
  float lm = -FLT_MAX;
#pragma unroll
  for (int k = 0; k < NK; ++k)
    lm = fmaxf(lm, fmaxf(fmaxf(U.v[k].x, U.v[k].y), fmaxf(U.v[k].z, U.v[k].w)));
#pragma unroll
  for (int off = 32; off; off >>= 1) lm = fmaxf(lm, __shfl_xor(lm, off));
  const float m1 = lm;
  const float nm1l = -m1 * LOG2E;

  // exp-sum + eq-based (m2, argmax, dup-count)
  float Z = 0.f, m2 = -FLT_MAX;
  int idx = INT_MAX, cnt = 0;
#pragma unroll
  for (int k = 0; k < NK; ++k) {
    const int base = 4 * (lane + 64 * k);
    const float a0 = U.v[k].x, a1 = U.v[k].y, a2 = U.v[k].z, a3 = U.v[k].w;
    // sentinel -FLT_MAX: fma overflows to -inf -> exp2 = 0, no NaN (m1 finite)
    Z += (fast_exp2(fmaf(a0, LOG2E, nm1l)) + fast_exp2(fmaf(a1, LOG2E, nm1l))) +
         (fast_exp2(fmaf(a2, LOG2E, nm1l)) + fast_exp2(fmaf(a3, LOG2E, nm1l)));
    const bool e0 = (a0 == m1), e1 = (a1 == m1), e2 = (a2 == m1), e3 = (a3 == m1);
    cnt += (int)e0 + (int)e1 + (int)e2 + (int)e3;
    m2 = fmaxf(m2, fmaxf(e0 ? -FLT_MAX : a0, e1 ? -FLT_MAX : a1));
    m2 = fmaxf(m2, fmaxf(e2 ? -FLT_MAX : a2, e3 ? -FLT_MAX : a3));
    const int i01 = min(e0 ? base     : INT_MAX, e1 ? base + 1 : INT_MAX);
    const int i23 = min(e2 ? base + 2 : INT_MAX, e3 ? base + 3 : INT_MAX);
    idx = min(idx, min(i01, i23));
  }
  // combined butterfly
#pragma unroll
  for (int off = 32; off; off >>= 1) {
    Z   += __shfl_xor(Z, off);
    m2   = fmaxf(m2, __shfl_xor(m2, off));
    cnt += __shfl_xor(cnt, off);
    idx  = min(idx, __shfl_xor(idx, off));
  }
  if (cnt >= 2) m2 = m1;   // duplicated max -> true second value == max

  const float invZ = 1.0f / Z;
  return make_float4(invZ,                                      // p_top1
                     fast_exp2((m2 - m1) * LOG2E) * invZ,       // p_top2
                     fast_exp2(fmaf(U.xt, LOG2E, nm1l)) * invZ, // p_target
                     __int_as_float(idx));                      // argmax
}

template<int NK, int C4, int NSTEP>
__device__ inline void pipe_run(const float* (&rp)[NSTEP], int (&tg)[NSTEP],
                                int (&oi)[NSTEP], int lane, float4* __restrict__ out4) {
  UnitData<NK> A, B;
  unit_load<NK, C4>(rp[0], lane, tg[0], A);
#pragma unroll
  for (int step = 0; step < NSTEP; ++step) {
    if (step + 1 < NSTEP) unit_load<NK, C4>(rp[step + 1], lane, tg[step + 1], B);
    const float4 res = unit_compute<NK>(A, lane);
    if (lane == 0) out4[oi[step]] = res;
    A = B;
  }
}

// grid = 5120 blocks x 256: waves 0..16383 = ENT (4 units each, s then o),
// waves 16384..20479 = REL (8 units each). Equal per-wave work.
__global__ __launch_bounds__(256, 8) void stats_pipe_kernel(
    const float* __restrict__ s, const float* __restrict__ r, const float* __restrict__ o,
    const int* __restrict__ st, const int* __restrict__ rt, const int* __restrict__ ot,
    float4* __restrict__ out4) {
  const int lane = threadIdx.x & 63;
  const int gw   = blockIdx.x * 4 + (threadIdx.x >> 6);
  if (gw < 16384) {
    const float* rp[4]; int tg[4]; int oi[4];
#pragma unroll
    for (int t = 0; t < 4; ++t) {
      const int u   = gw + 16384 * t;
      const int m   = u >> 15;          // 0: s, 1: o
      const int row = u & (B - 1);
      rp[t] = (m ? o : s) + (size_t)row * C_ENT;
      tg[t] = (m ? ot : st)[row];       // scalar preload, off the prefetch path
      oi[t] = m * B + row;
    }
    pipe_run<4, C_ENT / 4, 4>(rp, tg, oi, lane, out4);
  } else {
    const int w2 = gw - 16384;          // [0, 4096)
    const float* rp[8]; int tg[8]; int oi[8];
#pragma unroll
    for (int t = 0; t < 8; ++t) {
      const int row = w2 + 4096 * t;
      rp[t] = r + (size_t)row * C_REL;
      tg[t] = rt[row];
      oi[t] = 2 * B + row;
    }
    pipe_run<2, C_REL / 4, 8>(rp, tg, oi, lane, out4);
  }
}

__global__ __launch_bounds__(256) void combine_kernel(
    const float4* __restrict__ stat4,
    const int* __restrict__ st, const int* __restrict__ rt, const int* __restrict__ ot,
    float* __restrict__ partial) {
  const int row = blockIdx.x * 256 + threadIdx.x;   // grid = B/256
  const float4 S = stat4[row];
  const float4 O = stat4[B + row];
  const float4 R = stat4[2 * B + row];
  const float gt   = S.z * R.z * O.z;
  const float top1 = S.x * R.x * O.x;
  // second-smallest of the 8 top2-products = min of the three one-swap products
  const float c1 = S.x * R.y * O.y;
  const float c2 = S.y * R.x * O.y;
  const float c3 = S.y * R.y * O.x;
  const float second = fminf(c1, fminf(c2, c3));
  const bool cond = (__float_as_int(S.w) == st[row]) &&
                    (__float_as_int(R.w) == rt[row]) &&
                    (__float_as_int(O.w) == ot[row]);
  const float pre = cond ? second : top1;
  partial[row] = fmaxf(1.0f - gt + pre, 0.0f);
}

__global__ __launch_bounds__(1024) void reduce_sum_kernel(const float* __restrict__ p,
                                                          float* __restrict__ out) {
  const float4* p4 = (const float4*)p;
  float sum = 0.f;
  for (int i = threadIdx.x; i < B / 4; i += 1024) {
    const float4 v = p4[i];
    sum += (v.x + v.y) + (v.z + v.w);
  }
#pragma unroll
  for (int off = 32; off > 0; off >>= 1) sum += __shfl_xor(sum, off);
  __shared__ float lds[16];
  if ((threadIdx.x & 63) == 0) lds[threadIdx.x >> 6] = sum;
  __syncthreads();
  if (threadIdx.x == 0) {
    float t = 0.f;
#pragma unroll
    for (int i = 0; i < 16; ++i) t += lds[i];
    out[0] = t * (1.0f / (float)B);
  }
}

// ---------------- fallback (ws too small): one wave per row, atomic ----------------

__device__ inline void combine_stats(float& m1, int& i1, float& m2, float& Z,
                                     float bm1, int bi1, float bm2, float bZ) {
  bool bwin = (bm1 > m1) || (bm1 == m1 && bi1 < i1);
  float wm1 = bwin ? bm1 : m1;
  int   wi1 = bwin ? bi1 : i1;
  float wm2 = bwin ? bm2 : m2;
  float lm1 = bwin ? m1  : bm1;
  float wZ  = bwin ? bZ  : Z;
  float lZ  = bwin ? Z   : bZ;
  m1 = wm1; i1 = wi1;
  m2 = fmaxf(wm2, lm1);
  Z  = wZ + lZ * __expf(lm1 - wm1);
}

template<int NK, int C4>
__device__ inline void row_stats(const float* __restrict__ row, int lane, int target,
                                 float& p_top1, float& p_top2, int& amax, float& p_tgt) {
  const float4* row4 = (const float4*)row;
  float4 v[NK];
#pragma unroll
  for (int k = 0; k < NK; ++k) {
    int idx = lane + 64 * k;
    v[k] = (idx < C4) ? row4[idx] : make_float4(-FLT_MAX, -FLT_MAX, -FLT_MAX, -FLT_MAX);
  }
  float m1 = -FLT_MAX, m2 = -FLT_MAX;
  int   i1 = 0x7fffffff;
#pragma unroll
  for (int k = 0; k < NK; ++k) {
    int base = 4 * (lane + 64 * k);
    float a0 = v[k].x, a1 = v[k].y, a2 = v[k].z, a3 = v[k].w;
    if (a0 > m1) { m2 = m1; m1 = a0; i1 = base;     } else if (a0 > m2) m2 = a0;
    if (a1 > m1) { m2 = m1; m1 = a1; i1 = base + 1; } else if (a1 > m2) m2 = a1;
    if (a2 > m1) { m2 = m1; m1 = a2; i1 = base + 2; } else if (a2 > m2) m2 = a2;
    if (a3 > m1) { m2 = m1; m1 = a3; i1 = base + 3; } else if (a3 > m2) m2 = a3;
  }
  float Z = 0.f;
#pragma unroll
  for (int k = 0; k < NK; ++k) {
    Z += __expf(v[k].x - m1); Z += __expf(v[k].y - m1);
    Z += __expf(v[k].z - m1); Z += __expf(v[k].w - m1);
  }
#pragma unroll
  for (int off = 32; off > 0; off >>= 1) {
    float bm1 = __shfl_xor(m1, off);
    int   bi1 = __shfl_xor(i1, off);
    float bm2 = __shfl_xor(m2, off);
    float bZ  = __shfl_xor(Z,  off);
    combine_stats(m1, i1, m2, Z, bm1, bi1, bm2, bZ);
  }
  float invZ = 1.0f / Z;
  float xt   = row[target];
  p_top1 = invZ;
  p_top2 = __expf(m2 - m1) * invZ;
  p_tgt  = __expf(xt - m1) * invZ;
  amax   = i1;
}

__global__ __launch_bounds__(256) void rank_loss_atomic_kernel(
    const float* __restrict__ s, const float* __restrict__ r, const float* __restrict__ o,
    const int* __restrict__ st, const int* __restrict__ rt, const int* __restrict__ ot,
    float* __restrict__ out) {
  const int wid  = threadIdx.x >> 6;
  const int lane = threadIdx.x & 63;
  const int row  = blockIdx.x * 4 + wid;

  const int tS = st[row], tR = rt[row], tO = ot[row];
  float sp0, sp1, spt; int sa;
  float rp0, rp1, rpt; int ra;
  float op0, op1, opt; int oa;
  row_stats<4, C_ENT / 4>(s + (size_t)row * C_ENT, lane, tS, sp0, sp1, sa, spt);
  row_stats<2, C_REL / 4>(r + (size_t)row * C_REL, lane, tR, rp0, rp1, ra, rpt);
  row_stats<4, C_ENT / 4>(o + (size_t)row * C_ENT, lane, tO, op0, op1, oa, opt);

  if (lane == 0) {
    float gt   = spt * rpt * opt;
    float top1 = sp0 * rp0 * op0;
    float c1 = sp0 * rp1 * op1;
    float c2 = sp1 * rp0 * op1;
    float c3 = sp1 * rp1 * op0;
    float second = fminf(c1, fminf(c2, c3));
    bool cond = (sa == tS) && (ra == tR) && (oa == tO);
    float pre = cond ? second : top1;
    atomicAdd(out, fmaxf(1.0f - gt + pre, 0.0f) * (1.0f / (float)B));
  }
}

extern "C" void kernel_launch(void* const* d_in, const int* in_sizes, int n_in,
                              void* d_out, int out_size, void* d_ws, size_t ws_size,
                              hipStream_t stream) {
  const float* s  = (const float*)d_in[0];
  const float* r  = (const float*)d_in[1];
  const float* o  = (const float*)d_in[2];
  const int*   st = (const int*)d_in[3];
  const int*   rt = (const int*)d_in[4];
  const int*   ot = (const int*)d_in[5];
  float* out = (float*)d_out;

  const size_t statBytes = (size_t)3 * B * sizeof(float4);   // 1.5 MiB
  if (ws_size >= statBytes + (size_t)B * sizeof(float)) {
    float4* stat4  = (float4*)d_ws;
    float* partial = (float*)((char*)d_ws + statBytes);
    stats_pipe_kernel<<<5120, 256, 0, stream>>>(s, r, o, st, rt, ot, stat4);
    combine_kernel<<<B / 256, 256, 0, stream>>>(stat4, st, rt, ot, partial);
    reduce_sum_kernel<<<1, 1024, 0, stream>>>(partial, out);
  } else {
    hipMemsetAsync(d_out, 0, sizeof(float), stream);
    rank_loss_atomic_kernel<<<B / 4, 256, 0, stream>>>(s, r, o, st, rt, ot, out);
  }
}